// Round 4
// baseline (119.699 us; speedup 1.0000x reference)
//
#include <hip/hip_runtime.h>
#include <hip/hip_bf16.h>
#include <stdint.h>

#define IN_F   128
#define OUT_F  128
#define NUM_F  8
#define NROWS  (16*4096)

typedef __bf16  bf16x8  __attribute__((ext_vector_type(8)));
typedef float   f32x16  __attribute__((ext_vector_type(16)));

// Wp layout: [half][fb][s][t][lane][8 bf16]; half-stride = 9*8*2*64*16 = 147456 B
#define LDS_HALF  (9*8*2*64*16)
#define WP_CHUNKS (2*9*8*2*64)
#define WP_BYTES  (WP_CHUNKS*16)
#define BIAS_OFF  WP_BYTES

// ---------------- prep: build permuted bf16 weight + bias ----------------
__global__ __launch_bounds__(256) void skan_prep(
    const float* __restrict__ base_w,   // [OUT_F][IN_F]
    const float* __restrict__ scale,    // [OUT_F]
    const float* __restrict__ coef,     // [GROUPS][1][NUM_F]
    const float* __restrict__ conv_w,   // [NUM_F][OUT_F][IN_F]
    const float* __restrict__ conv_b,   // [NUM_F][OUT_F]
    __bf16* __restrict__ Wp, float* __restrict__ bias)
{
    int gid = blockIdx.x * 256 + threadIdx.x;        // 0..18431
    int flat = gid;
    int l  = flat & 63;  flat >>= 6;
    int t2 = flat & 1;   flat >>= 1;
    int s  = flat & 7;   flat >>= 3;
    int fb = flat % 9;
    int h2 = flat / 9;                               // out-half
    int n  = h2 * 64 + t2 * 32 + (l & 31);           // global out col
    int k0 = s * 16 + (l >> 5) * 8;
    __bf16* dst = Wp + (size_t)gid * 8;
    if (fb == 0) {
        const float4* b4 = (const float4*)(base_w + n * IN_F + k0);
        float4 a = b4[0], b = b4[1];
        dst[0]=(__bf16)a.x; dst[1]=(__bf16)a.y; dst[2]=(__bf16)a.z; dst[3]=(__bf16)a.w;
        dst[4]=(__bf16)b.x; dst[5]=(__bf16)b.y; dst[6]=(__bf16)b.z; dst[7]=(__bf16)b.w;
    } else {
        int f = fb - 1;
        float sc = scale[n];
        const float4* c4 = (const float4*)(conv_w + ((size_t)f * OUT_F + n) * IN_F + k0);
        float4 a = c4[0], b = c4[1];
        float m0c = coef[((k0    ) >> 4) * NUM_F + f] * sc;  // k0..k0+7 same group? group = k/16
        float m1c = coef[((k0 + 4) >> 4) * NUM_F + f] * sc;  // k0 is 8-aligned: k0..k0+7 spans one 16-group half
        // group size 16, k0 multiple of 8 -> all 8 k's are in group (k0>>4)
        (void)m1c;
        dst[0]=(__bf16)(a.x*m0c); dst[1]=(__bf16)(a.y*m0c); dst[2]=(__bf16)(a.z*m0c); dst[3]=(__bf16)(a.w*m0c);
        dst[4]=(__bf16)(b.x*m0c); dst[5]=(__bf16)(b.y*m0c); dst[6]=(__bf16)(b.z*m0c); dst[7]=(__bf16)(b.w*m0c);
    }
    if (gid < OUT_F) {
        float b = 0.f;
        #pragma unroll
        for (int f = 0; f < NUM_F; ++f) b += conv_b[f * OUT_F + gid];
        bias[gid] = b * scale[gid];
    }
}

// ---------------- main fused kernel ----------------
__device__ __forceinline__ void gld_lds16(const void* g, void* l) {
    __builtin_amdgcn_global_load_lds(
        (const __attribute__((address_space(1))) uint32_t*)g,
        (__attribute__((address_space(3))) uint32_t*)l, 16, 0, 0);
}

__device__ __forceinline__ uint32_t pkbf(float a, float b) {
    __bf16 x = (__bf16)a, y = (__bf16)b;
    uint16_t ux, uy;
    __builtin_memcpy(&ux, &x, 2);
    __builtin_memcpy(&uy, &y, 2);
    return (uint32_t)ux | ((uint32_t)uy << 16);
}
__device__ __forceinline__ float upk_lo(uint32_t p) { return __uint_as_float(p << 16); }
__device__ __forceinline__ float upk_hi(uint32_t p) { return __uint_as_float(p & 0xffff0000u); }

__global__ __launch_bounds__(256, 1) void skan_main(
    const float* __restrict__ x,        // [NROWS][IN_F]
    const __bf16* __restrict__ Wp,
    const float* __restrict__ bias,
    float* __restrict__ out)            // [NROWS][OUT_F]
{
    // ALL weights for this block's out-half resident: 144 KB (gfx950 GROUP seg = 160 KB)
    __shared__ __align__(16) char sB[LDS_HALF];

    const int tid  = threadIdx.x;
    const int w    = tid >> 6;          // wave 0..3
    const int l    = tid & 63;
    const int hl   = l & 31;
    const int h    = l >> 5;
    const int bx   = blockIdx.x;
    const int half = bx & 1;            // out-col half
    const int m0   = (bx >> 1) * 256 + w * 64;   // wave's 64-row base

    // ---- stage all 9 fb weight blocks for this half (36 x 16B/lane) ----
    const char* src = (const char*)Wp + (size_t)half * LDS_HALF;
    #pragma unroll
    for (int i = 0; i < 36; ++i) {
        int off = (i * 256 + tid) * 16;
        gld_lds16(src + off, sB + off);
    }

    // ---- load x for rows m0+32g+hl, cols s*16 + h*8 + j; pack to bf16 ----
    const float4* x4 = (const float4*)x;
    uint32_t xe[2][32];                 // [g][s*4 + jp]
    #pragma unroll
    for (int g = 0; g < 2; ++g) {
        size_t base = (size_t)(m0 + 32 * g + hl) * 32 + 2 * h;
        #pragma unroll
        for (int s = 0; s < 8; ++s) {
            float4 a = x4[base + 4 * s];
            float4 b = x4[base + 4 * s + 1];
            xe[g][4*s+0] = pkbf(a.x, a.y);
            xe[g][4*s+1] = pkbf(a.z, a.w);
            xe[g][4*s+2] = pkbf(b.x, b.y);
            xe[g][4*s+3] = pkbf(b.z, b.w);
        }
    }

    f32x16 acc[2][2];
    #pragma unroll
    for (int g = 0; g < 2; ++g)
        #pragma unroll
        for (int t = 0; t < 2; ++t)
            #pragma unroll
            for (int r = 0; r < 16; ++r) acc[g][t][r] = 0.f;

    __syncthreads();   // staging drained; the ONLY barrier

    const bf16x8* bp = (const bf16x8*)sB;

    // ---- fb0: silu path ----
    #pragma unroll
    for (int s = 0; s < 8; ++s) {
        bf16x8 a0, a1;
        #pragma unroll
        for (int g = 0; g < 2; ++g) {
            #pragma unroll
            for (int jp = 0; jp < 4; ++jp) {
                uint32_t p = xe[g][4*s+jp];
                float lo = upk_lo(p), hi = upk_hi(p);
                float slo = lo * __builtin_amdgcn_rcpf(1.0f + __expf(-lo));
                float shi = hi * __builtin_amdgcn_rcpf(1.0f + __expf(-hi));
                if (g == 0) { a0[2*jp] = (__bf16)slo; a0[2*jp+1] = (__bf16)shi; }
                else        { a1[2*jp] = (__bf16)slo; a1[2*jp+1] = (__bf16)shi; }
            }
        }
        #pragma unroll
        for (int t = 0; t < 2; ++t) {
            bf16x8 b = bp[(s * 2 + t) * 64 + l];
            acc[0][t] = __builtin_amdgcn_mfma_f32_32x32x16_bf16(a0, b, acc[0][t], 0, 0, 0);
            acc[1][t] = __builtin_amdgcn_mfma_f32_32x32x16_bf16(a1, b, acc[1][t], 0, 0, 0);
        }
    }

    // ---- spline: sin(f*x) via Chebyshev recurrence s_f = 2cos(x)*s_{f-1} - s_{f-2} ----
    #pragma unroll
    for (int s = 0; s < 8; ++s) {
        float sp[16], sp2[16], tc[16];   // idx = g*8 + j
        #pragma unroll
        for (int g = 0; g < 2; ++g) {
            #pragma unroll
            for (int jp = 0; jp < 4; ++jp) {
                uint32_t p = xe[g][4*s+jp];
                float lo = upk_lo(p), hi = upk_hi(p);
                float rl = __builtin_amdgcn_fractf(lo * 0.15915494309189535f);
                float rh = __builtin_amdgcn_fractf(hi * 0.15915494309189535f);
                int j0 = g * 8 + 2 * jp;
                sp[j0]     = __builtin_amdgcn_sinf(rl);
                sp[j0+1]   = __builtin_amdgcn_sinf(rh);
                tc[j0]     = 2.0f * __builtin_amdgcn_cosf(rl);
                tc[j0+1]   = 2.0f * __builtin_amdgcn_cosf(rh);
                sp2[j0]    = 0.0f;
                sp2[j0+1]  = 0.0f;
            }
        }
        #pragma unroll
        for (int f = 1; f <= 8; ++f) {
            bf16x8 a0, a1;
            #pragma unroll
            for (int j = 0; j < 8; ++j) {
                a0[j] = (__bf16)sp[j];
                a1[j] = (__bf16)sp[8 + j];
            }
            #pragma unroll
            for (int t = 0; t < 2; ++t) {
                bf16x8 b = bp[((f * 8 + s) * 2 + t) * 64 + l];
                acc[0][t] = __builtin_amdgcn_mfma_f32_32x32x16_bf16(a0, b, acc[0][t], 0, 0, 0);
                acc[1][t] = __builtin_amdgcn_mfma_f32_32x32x16_bf16(a1, b, acc[1][t], 0, 0, 0);
            }
            if (f < 8) {
                #pragma unroll
                for (int i = 0; i < 16; ++i) {
                    float sn = __builtin_fmaf(tc[i], sp[i], -sp2[i]);
                    sp2[i] = sp[i];
                    sp[i]  = sn;
                }
            }
        }
    }

    // ---- epilogue: direct strided stores (128-B contiguous per half-wave) ----
    // D layout: col = lane&31, row = (r&3) + 8*(r>>2) + 4*h (+32g)
    #pragma unroll
    for (int g = 0; g < 2; ++g) {
        #pragma unroll
        for (int t = 0; t < 2; ++t) {
            float bv = bias[half * 64 + t * 32 + hl];
            #pragma unroll
            for (int r = 0; r < 16; ++r) {
                int row = (r & 3) + 8 * (r >> 2) + 4 * h + 32 * g;
                out[(size_t)(m0 + row) * OUT_F + half * 64 + t * 32 + hl] = acc[g][t][r] + bv;
            }
        }
    }
}

extern "C" void kernel_launch(void* const* d_in, const int* in_sizes, int n_in,
                              void* d_out, int out_size, void* d_ws, size_t ws_size,
                              hipStream_t stream) {
    const float* x      = (const float*)d_in[0];
    // d_in[1] = grid (values 1..8, folded into the recurrence)
    const float* base_w = (const float*)d_in[2];
    const float* scale  = (const float*)d_in[3];
    const float* coef   = (const float*)d_in[4];
    const float* conv_w = (const float*)d_in[5];
    const float* conv_b = (const float*)d_in[6];
    __bf16* Wp   = (__bf16*)d_ws;
    float*  bias = (float*)((char*)d_ws + BIAS_OFF);
    float*  out  = (float*)d_out;

    skan_prep<<<WP_CHUNKS / 256, 256, 0, stream>>>(base_w, scale, coef, conv_w, conv_b, Wp, bias);
    // 256 row-groups x 2 out-halves; adjacent pairs share rows (L3 x locality)
    skan_main<<<(NROWS / 256) * 2, 256, 0, stream>>>(x, Wp, bias, out);
}

// Round 5
// 117.254 us; speedup vs baseline: 1.0209x; 1.0209x over previous
//
#include <hip/hip_runtime.h>
#include <hip/hip_bf16.h>
#include <stdint.h>

#define IN_F   128
#define OUT_F  128
#define NUM_F  8
#define NROWS  (16*4096)

typedef __bf16  bf16x8  __attribute__((ext_vector_type(8)));
typedef float   f32x16  __attribute__((ext_vector_type(16)));

// Wp layout: [half][fb][s][t][lane][8 bf16]; half-stride = 9*8*2*64*16 = 147456 B
#define LDS_HALF  (9*8*2*64*16)
#define WP_CHUNKS (2*9*8*2*64)
#define WP_BYTES  (WP_CHUNKS*16)
#define BIAS_OFF  WP_BYTES

// ---------------- prep: build permuted bf16 weight + bias ----------------
__global__ __launch_bounds__(256) void skan_prep(
    const float* __restrict__ base_w,   // [OUT_F][IN_F]
    const float* __restrict__ scale,    // [OUT_F]
    const float* __restrict__ coef,     // [GROUPS][1][NUM_F]
    const float* __restrict__ conv_w,   // [NUM_F][OUT_F][IN_F]
    const float* __restrict__ conv_b,   // [NUM_F][OUT_F]
    __bf16* __restrict__ Wp, float* __restrict__ bias)
{
    int gid = blockIdx.x * 256 + threadIdx.x;        // 0..18431
    int flat = gid;
    int l  = flat & 63;  flat >>= 6;
    int t2 = flat & 1;   flat >>= 1;
    int s  = flat & 7;   flat >>= 3;
    int fb = flat % 9;
    int h2 = flat / 9;                               // out-half
    int n  = h2 * 64 + t2 * 32 + (l & 31);           // global out col
    int k0 = s * 16 + (l >> 5) * 8;
    __bf16* dst = Wp + (size_t)gid * 8;
    if (fb == 0) {
        const float4* b4 = (const float4*)(base_w + n * IN_F + k0);
        float4 a = b4[0], b = b4[1];
        dst[0]=(__bf16)a.x; dst[1]=(__bf16)a.y; dst[2]=(__bf16)a.z; dst[3]=(__bf16)a.w;
        dst[4]=(__bf16)b.x; dst[5]=(__bf16)b.y; dst[6]=(__bf16)b.z; dst[7]=(__bf16)b.w;
    } else {
        int f = fb - 1;
        float sc = scale[n];
        const float4* c4 = (const float4*)(conv_w + ((size_t)f * OUT_F + n) * IN_F + k0);
        float4 a = c4[0], b = c4[1];
        // group = k/16; k0 is 8-aligned so all 8 k's share group (k0>>4)
        float mc = coef[(k0 >> 4) * NUM_F + f] * sc;
        dst[0]=(__bf16)(a.x*mc); dst[1]=(__bf16)(a.y*mc); dst[2]=(__bf16)(a.z*mc); dst[3]=(__bf16)(a.w*mc);
        dst[4]=(__bf16)(b.x*mc); dst[5]=(__bf16)(b.y*mc); dst[6]=(__bf16)(b.z*mc); dst[7]=(__bf16)(b.w*mc);
    }
    if (gid < OUT_F) {
        float b = 0.f;
        #pragma unroll
        for (int f = 0; f < NUM_F; ++f) b += conv_b[f * OUT_F + gid];
        bias[gid] = b * scale[gid];
    }
}

// ---------------- main fused kernel ----------------
__device__ __forceinline__ void gld_lds16(const void* g, void* l) {
    __builtin_amdgcn_global_load_lds(
        (const __attribute__((address_space(1))) uint32_t*)g,
        (__attribute__((address_space(3))) uint32_t*)l, 16, 0, 0);
}

__device__ __forceinline__ uint32_t pkbf(float a, float b) {
    __bf16 x = (__bf16)a, y = (__bf16)b;
    uint16_t ux, uy;
    __builtin_memcpy(&ux, &x, 2);
    __builtin_memcpy(&uy, &y, 2);
    return (uint32_t)ux | ((uint32_t)uy << 16);
}
__device__ __forceinline__ float upk_lo(uint32_t p) { return __uint_as_float(p << 16); }
__device__ __forceinline__ float upk_hi(uint32_t p) { return __uint_as_float(p & 0xffff0000u); }

// 1024 threads (16 waves), min 4 waves/EU -> VGPR <= 128, 4 waves/SIMD resident
__global__ __launch_bounds__(1024, 4) void skan_main(
    const float* __restrict__ x,        // [NROWS][IN_F]
    const __bf16* __restrict__ Wp,
    const float* __restrict__ bias,
    float* __restrict__ out)            // [NROWS][OUT_F]
{
    // this block's out-half weights, fully resident: 144 KB
    __shared__ __align__(16) char sB[LDS_HALF];

    const int tid  = threadIdx.x;
    const int w    = tid >> 6;          // wave 0..15
    const int l    = tid & 63;
    const int hl   = l & 31;
    const int h    = l >> 5;
    const int bx   = blockIdx.x;
    const int half = bx & 1;            // out-col half
    const int m0   = (bx >> 1) * 512 + w * 32;   // wave's 32-row base

    // ---- stage all 9 fb blocks for this half (9 x 16B per thread) ----
    const char* src = (const char*)Wp + (size_t)half * LDS_HALF;
    #pragma unroll
    for (int i = 0; i < 9; ++i) {
        int off = (i * 1024 + tid) * 16;        // wave-uniform base + l*16
        gld_lds16(src + off, sB + off);
    }

    // ---- load x rows m0+hl, cols s*16 + h*8 + j; pack to bf16 (32 VGPRs) ----
    const float4* x4 = (const float4*)x;
    uint32_t xe[32];                    // [s*4 + jp]
    {
        size_t base = (size_t)(m0 + hl) * 32 + 2 * h;
        #pragma unroll
        for (int s = 0; s < 8; ++s) {
            float4 a = x4[base + 4 * s];
            float4 b = x4[base + 4 * s + 1];
            xe[4*s+0] = pkbf(a.x, a.y);
            xe[4*s+1] = pkbf(a.z, a.w);
            xe[4*s+2] = pkbf(b.x, b.y);
            xe[4*s+3] = pkbf(b.z, b.w);
        }
    }

    f32x16 acc[2];
    #pragma unroll
    for (int t = 0; t < 2; ++t)
        #pragma unroll
        for (int r = 0; r < 16; ++r) acc[t][r] = 0.f;

    __syncthreads();   // staging drained; the ONLY barrier

    const bf16x8* bp = (const bf16x8*)sB;

    #pragma unroll
    for (int s = 0; s < 8; ++s) {
        // ---- fb0: silu path ----
        {
            bf16x8 a;
            #pragma unroll
            for (int jp = 0; jp < 4; ++jp) {
                uint32_t p = xe[4*s+jp];
                float lo = upk_lo(p), hi = upk_hi(p);
                a[2*jp]   = (__bf16)(lo * __builtin_amdgcn_rcpf(1.0f + __expf(-lo)));
                a[2*jp+1] = (__bf16)(hi * __builtin_amdgcn_rcpf(1.0f + __expf(-hi)));
            }
            #pragma unroll
            for (int t = 0; t < 2; ++t) {
                bf16x8 b = bp[(s * 2 + t) * 64 + l];
                acc[t] = __builtin_amdgcn_mfma_f32_32x32x16_bf16(a, b, acc[t], 0, 0, 0);
            }
        }
        // ---- spline: sin(f*x) via s_f = 2cos(x)*s_{f-1} - s_{f-2} ----
        float sp[8], sp2[8], tc[8];
        #pragma unroll
        for (int jp = 0; jp < 4; ++jp) {
            uint32_t p = xe[4*s+jp];
            float lo = upk_lo(p), hi = upk_hi(p);
            float rl = __builtin_amdgcn_fractf(lo * 0.15915494309189535f);
            float rh = __builtin_amdgcn_fractf(hi * 0.15915494309189535f);
            sp[2*jp]    = __builtin_amdgcn_sinf(rl);
            sp[2*jp+1]  = __builtin_amdgcn_sinf(rh);
            tc[2*jp]    = 2.0f * __builtin_amdgcn_cosf(rl);
            tc[2*jp+1]  = 2.0f * __builtin_amdgcn_cosf(rh);
            sp2[2*jp]   = 0.0f;
            sp2[2*jp+1] = 0.0f;
        }
        #pragma unroll
        for (int f = 1; f <= 8; ++f) {
            bf16x8 a;
            #pragma unroll
            for (int j = 0; j < 8; ++j) a[j] = (__bf16)sp[j];
            #pragma unroll
            for (int t = 0; t < 2; ++t) {
                bf16x8 b = bp[((f * 8 + s) * 2 + t) * 64 + l];
                acc[t] = __builtin_amdgcn_mfma_f32_32x32x16_bf16(a, b, acc[t], 0, 0, 0);
            }
            if (f < 8) {
                #pragma unroll
                for (int i = 0; i < 8; ++i) {
                    float sn = __builtin_fmaf(tc[i], sp[i], -sp2[i]);
                    sp2[i] = sp[i];
                    sp[i]  = sn;
                }
            }
        }
    }

    // ---- epilogue: direct stores (128-B contiguous per half-wave) ----
    // D layout: col = lane&31, row = (r&3) + 8*(r>>2) + 4*h
    #pragma unroll
    for (int t = 0; t < 2; ++t) {
        float bv = bias[half * 64 + t * 32 + hl];
        #pragma unroll
        for (int r = 0; r < 16; ++r) {
            int row = (r & 3) + 8 * (r >> 2) + 4 * h;
            out[(size_t)(m0 + row) * OUT_F + half * 64 + t * 32 + hl] = acc[t][r] + bv;
        }
    }
}

extern "C" void kernel_launch(void* const* d_in, const int* in_sizes, int n_in,
                              void* d_out, int out_size, void* d_ws, size_t ws_size,
                              hipStream_t stream) {
    const float* x      = (const float*)d_in[0];
    // d_in[1] = grid (values 1..8, folded into the recurrence)
    const float* base_w = (const float*)d_in[2];
    const float* scale  = (const float*)d_in[3];
    const float* coef   = (const float*)d_in[4];
    const float* conv_w = (const float*)d_in[5];
    const float* conv_b = (const float*)d_in[6];
    __bf16* Wp   = (__bf16*)d_ws;
    float*  bias = (float*)((char*)d_ws + BIAS_OFF);
    float*  out  = (float*)d_out;

    skan_prep<<<WP_CHUNKS / 256, 256, 0, stream>>>(base_w, scale, coef, conv_w, conv_b, Wp, bias);
    // 128 row-blocks x 2 out-halves = 256 blocks, one per CU, 16 waves each
    skan_main<<<(NROWS / 512) * 2, 1024, 0, stream>>>(x, Wp, bias, out);
}